// Round 5
// baseline (168.737 us; speedup 1.0000x reference)
//
#include <hip/hip_runtime.h>
#include <stdint.h>

#define C_DIM 512
#define HW_N  1024
#define CPG   64
#define EPS_GN 1e-5f
#define SCALE_QK 0.044194173824159216f   // 512^-0.5

typedef __attribute__((ext_vector_type(8))) __bf16 bf16x8v;
typedef __attribute__((ext_vector_type(4))) float  f32x4;

typedef __attribute__((address_space(1))) void gvoid_t;
typedef __attribute__((address_space(3))) void lvoid_t;

__device__ __forceinline__ void gload_lds16(const void* g, void* l) {
  __builtin_amdgcn_global_load_lds((gvoid_t*)g, (lvoid_t*)l, 16, 0, 0);
}

__device__ __forceinline__ uint16_t f2bfbits(float f) {
  __bf16 h = (__bf16)f;
  return __builtin_bit_cast(uint16_t, h);
}

__device__ __forceinline__ float bf2f(uint16_t u) {
  return __builtin_bit_cast(float, (uint32_t)u << 16);
}

template<int N>
__device__ __forceinline__ void vm_wait() {
  if constexpr (N == 0)      asm volatile("s_waitcnt vmcnt(0)" ::: "memory");
  else if constexpr (N == 3) asm volatile("s_waitcnt vmcnt(3)" ::: "memory");
  else if constexpr (N == 4) asm volatile("s_waitcnt vmcnt(4)" ::: "memory");
  else if constexpr (N == 6) asm volatile("s_waitcnt vmcnt(6)" ::: "memory");
}

// ---------------------------------------------------------------------------
// GN stats: 256 blocks = (b, g, half). Deterministic fp32 partials.
// ---------------------------------------------------------------------------
__global__ __launch_bounds__(256)
void gn_stats(const float* __restrict__ x, float2* __restrict__ part)
{
  const int lin  = blockIdx.x;
  const int b    = lin >> 4;
  const int g    = (lin >> 1) & 7;
  const int half = lin & 1;
  const int t    = threadIdx.x;

  const float4* xv = (const float4*)(x + ((long long)(b * C_DIM + g * CPG)) * HW_N
                                       + half * 512);
  float s1 = 0.f, s2 = 0.f;
  for (int i = t; i < 64 * 128; i += 256) {
    const int c  = i >> 7;
    const int nf = i & 127;
    float4 v = xv[c * 256 + nf];
    s1 += v.x + v.y + v.z + v.w;
    s2 += v.x * v.x + v.y * v.y + v.z * v.z + v.w * v.w;
  }
  #pragma unroll
  for (int off = 32; off; off >>= 1) {
    s1 += __shfl_xor(s1, off);
    s2 += __shfl_xor(s2, off);
  }
  __shared__ float red[2][4];
  const int w = t >> 6, l = t & 63;
  if (l == 0) { red[0][w] = s1; red[1][w] = s2; }
  __syncthreads();
  if (t == 0) {
    s1 = red[0][0] + red[0][1] + red[0][2] + red[0][3];
    s2 = red[1][0] + red[1][1] + red[1][2] + red[1][3];
    part[lin] = make_float2(s1, s2);
  }
}

// ---------------------------------------------------------------------------
// GN normalize + transpose -> hn^T bf16 [N][C], bf16x8 stores.
// ---------------------------------------------------------------------------
__global__ __launch_bounds__(512)
void gn_norm(const float* __restrict__ x, const float2* __restrict__ part,
             const float* __restrict__ gnw, const float* __restrict__ gnb,
             __bf16* __restrict__ hn)
{
  const int b  = blockIdx.x >> 4;
  const int nc = blockIdx.x & 15;
  const int t  = threadIdx.x;

  __shared__ float asc[512], bsc[512];
  __shared__ float tile[64][65];

  {
    const int c = t;
    const int g = c >> 6;
    float2 p0 = part[(b * 8 + g) * 2 + 0];
    float2 p1 = part[(b * 8 + g) * 2 + 1];
    const float mean = (p0.x + p1.x) * (1.f / 65536.f);
    const float var  = (p0.y + p1.y) * (1.f / 65536.f) - mean * mean;
    const float rstd = rsqrtf(var + EPS_GN);
    const float a = rstd * gnw[c];
    asc[c] = a;
    bsc[c] = gnb[c] - mean * a;
  }
  __syncthreads();

  const long long xb = (long long)b * C_DIM * HW_N + nc * 64;
  __bf16* ob = hn + ((long long)b * HW_N + nc * 64) * C_DIM;

  for (int cg = 0; cg < 8; ++cg) {
    #pragma unroll
    for (int pass = 0; pass < 2; ++pass) {
      const int task = pass * 512 + t;
      const int c  = task >> 4;
      const int f4 = task & 15;
      float4 v = *(const float4*)(x + xb + (long long)(cg * 64 + c) * HW_N + f4 * 4);
      const float a  = asc[cg * 64 + c];
      const float bb = bsc[cg * 64 + c];
      tile[c][f4 * 4 + 0] = v.x * a + bb;
      tile[c][f4 * 4 + 1] = v.y * a + bb;
      tile[c][f4 * 4 + 2] = v.z * a + bb;
      tile[c][f4 * 4 + 3] = v.w * a + bb;
    }
    __syncthreads();
    {
      const int n  = t >> 3;
      const int gc = t & 7;
      uint32_t p[4];
      #pragma unroll
      for (int j = 0; j < 4; ++j) {
        const float f0 = tile[gc * 8 + 2 * j + 0][n];
        const float f1 = tile[gc * 8 + 2 * j + 1][n];
        p[j] = (uint32_t)f2bfbits(f0) | ((uint32_t)f2bfbits(f1) << 16);
      }
      *(uint4*)(ob + (long long)n * C_DIM + cg * 64 + gc * 8) =
          make_uint4(p[0], p[1], p[2], p[3]);
    }
    __syncthreads();
  }
}

// ---------------------------------------------------------------------------
// Prep: 4 weight conversions (+scale fold on Wq) + bias concat.
// ---------------------------------------------------------------------------
__global__ __launch_bounds__(256)
void prep_kernel(const float* __restrict__ wq, const float* __restrict__ wk,
                 const float* __restrict__ wv, const float* __restrict__ wo,
                 const float* __restrict__ bq, const float* __restrict__ bk,
                 __bf16* __restrict__ wqkb, __bf16* __restrict__ wvb,
                 __bf16* __restrict__ wob, float* __restrict__ bqk)
{
  const int blk = blockIdx.x;
  if (blk < 1024) {
    const int which = blk >> 8;
    const int i = (blk & 255) * 256 + threadIdx.x;
    const float* src = (which == 0) ? wq : (which == 1) ? wk : (which == 2) ? wv : wo;
    __bf16* dst = (which == 0) ? wqkb
               : (which == 1) ? (wqkb + (size_t)C_DIM * C_DIM)
               : (which == 2) ? wvb : wob;
    const float scale = (which == 0) ? SCALE_QK : 1.f;
    float4 v = ((const float4*)src)[i];
    uint32_t lo = (uint32_t)f2bfbits(v.x * scale) | ((uint32_t)f2bfbits(v.y * scale) << 16);
    uint32_t hi = (uint32_t)f2bfbits(v.z * scale) | ((uint32_t)f2bfbits(v.w * scale) << 16);
    ((uint2*)dst)[i] = make_uint2(lo, hi);
  } else {
    for (int j = threadIdx.x; j < 1024; j += 256)
      bqk[j] = (j < 512) ? bq[j] * SCALE_QK : bk[j - 512];
  }
}

// ---------------------------------------------------------------------------
// Row softmax over bf16 S [rows][1024], in-place -> bf16 P.
// ---------------------------------------------------------------------------
__global__ __launch_bounds__(256)
void softmax_kernel(__bf16* __restrict__ S)
{
  const long long row = blockIdx.x;
  uint2* sp = (uint2*)(S + row * HW_N);
  const int t = threadIdx.x;
  uint2 raw = sp[t];
  float v0 = bf2f((uint16_t)(raw.x & 0xffff));
  float v1 = bf2f((uint16_t)(raw.x >> 16));
  float v2 = bf2f((uint16_t)(raw.y & 0xffff));
  float v3 = bf2f((uint16_t)(raw.y >> 16));
  float m = fmaxf(fmaxf(v0, v1), fmaxf(v2, v3));
  #pragma unroll
  for (int off = 32; off; off >>= 1) m = fmaxf(m, __shfl_xor(m, off));
  __shared__ float redm[4];
  __shared__ float reds[4];
  const int w = t >> 6, l = t & 63;
  if (l == 0) redm[w] = m;
  __syncthreads();
  m = fmaxf(fmaxf(redm[0], redm[1]), fmaxf(redm[2], redm[3]));
  float e0 = __expf(v0 - m), e1 = __expf(v1 - m);
  float e2 = __expf(v2 - m), e3 = __expf(v3 - m);
  float sum = e0 + e1 + e2 + e3;
  #pragma unroll
  for (int off = 32; off; off >>= 1) sum += __shfl_xor(sum, off);
  if (l == 0) reds[w] = sum;
  __syncthreads();
  sum = reds[0] + reds[1] + reds[2] + reds[3];
  const float inv = 1.f / sum;
  uint32_t lo = (uint32_t)f2bfbits(e0 * inv) | ((uint32_t)f2bfbits(e1 * inv) << 16);
  uint32_t hi = (uint32_t)f2bfbits(e2 * inv) | ((uint32_t)f2bfbits(e3 * inv) << 16);
  sp[t] = make_uint2(lo, hi);
}

// ---------------------------------------------------------------------------
// 8-phase 256x256 bf16 GEMM (m201-style): C[M][N] = A[M][K] x B[N][K]^T.
// BK=64, 8 waves (2M x 4N), 2-deep LDS dbuf (2 x 64KB), per K-tile 4 block-
// quadrant phases; stage 1 half-tile (128rows x 64k of A or B, 2 gloads)
// per phase; ONE vmcnt(6) per K-tile (3 half-tiles in flight). LDS rows
// 128B, swizzle granule ^= row&7 via inverse-swizzled global source.
// Stage/consume invariant (verified): entering tile t, all 4 halves of t
// landed; t+1's {A0,B0,B1} in flight; A1 of t+1 staged at t.P0; t+2's
// {A0,B0,B1} staged at t.{P1,P2,P3} into buf[t&1] regions after their
// last read (A0@P0, B0@P0, B1@P1) + phase barrier.
// BIASM: 0 none, 1 per-col, 2 per-row. Output bf16.
// ---------------------------------------------------------------------------
#define QMFMA(QA, QB, BREG)                                                    \
  do {                                                                         \
    __builtin_amdgcn_s_setprio(1);                                             \
    _Pragma("unroll")                                                          \
    for (int f_ = 0; f_ < 4; ++f_)                                             \
      _Pragma("unroll")                                                        \
      for (int c_ = 0; c_ < 2; ++c_)                                           \
        _Pragma("unroll")                                                      \
        for (int kk_ = 0; kk_ < 2; ++kk_)                                      \
          acc[QA][QB][f_][c_] = __builtin_amdgcn_mfma_f32_16x16x32_bf16(       \
              Ar[f_][kk_], BREG[c_][kk_], acc[QA][QB][f_][c_], 0, 0, 0);       \
    __builtin_amdgcn_s_setprio(0);                                             \
  } while (0)

#define LGKM0_FENCE()                                                          \
  asm volatile("s_waitcnt lgkmcnt(0)" ::: "memory");                           \
  __builtin_amdgcn_sched_barrier(0)

template<int BIASM>
__global__ __launch_bounds__(512, 2)
void gemm256(const __bf16* __restrict__ Amat, const __bf16* __restrict__ Bmat,
             __bf16* __restrict__ Cmat, const float* __restrict__ bias,
             int lda, int ldb, int ldc,
             long long aS, long long bS, long long cS, int K)
{
  __shared__ alignas(16) char lds[131072];   // 2 buf x [A0|A1|B0|B1] x 16KB

  const int tt = threadIdx.x;
  const int w  = tt >> 6;
  const int l  = tt & 63;
  const int lr = l & 15;
  const int lg = l >> 4;
  const int wm = w >> 2;      // 0..1
  const int wn = w & 3;       // 0..3
  const int b  = blockIdx.z;
  const int n0 = blockIdx.x * 256;
  const int m0 = blockIdx.y * 256;

  const __bf16* Ab = Amat + (long long)b * aS;
  const __bf16* Bb = Bmat + (long long)b * bS;

  // staging: thread covers rows r0 and r0+64 of a 128x64 half (2 x 16B),
  // source column granule inverse-swizzled so LDS stays linear (rule 21).
  const int r0  = tt >> 3;
  const int sg8 = ((tt & 7) ^ ((tt >> 3) & 7)) << 3;

  f32x4 acc[2][2][4][2];
  #pragma unroll
  for (int qa = 0; qa < 2; ++qa)
    #pragma unroll
    for (int qb = 0; qb < 2; ++qb)
      #pragma unroll
      for (int f = 0; f < 4; ++f)
        #pragma unroll
        for (int c = 0; c < 2; ++c)
          acc[qa][qb][f][c] = (f32x4){0.f, 0.f, 0.f, 0.f};

  auto stage = [&](int kt, int h) {   // h: 0=A0 1=A1 2=B0 3=B1
    char* dst = lds + ((kt & 1) << 16) + (h << 14) + w * 1024;
    const long long ld = (h < 2) ? lda : ldb;
    const __bf16* src = ((h < 2) ? Ab + (long long)(m0 + (h & 1) * 128) * lda
                                 : Bb + (long long)(n0 + (h & 1) * 128) * ldb)
                        + (long long)kt * 64 + sg8;
    gload_lds16(src + (long long)r0 * ld, dst);
    gload_lds16(src + (long long)(r0 + 64) * ld, dst + 8192);
  };
  auto rdA = [&](const char* bb, int qa, int f, int kk) -> bf16x8v {
    const int r = wm * 64 + f * 16 + lr;
    return *(const bf16x8v*)(bb + (qa << 14) + r * 128
                             + (((kk * 4 + lg) ^ (r & 7)) << 4));
  };
  auto rdB = [&](const char* bb, int qb, int c, int kk) -> bf16x8v {
    const int r = wn * 32 + c * 16 + lr;
    return *(const bf16x8v*)(bb + 32768 + (qb << 14) + r * 128
                             + (((kk * 4 + lg) ^ (r & 7)) << 4));
  };

  const int NT = K >> 6;

  // prologue: tile0 all 4 halves, tile1 {A0,B0,B1}
  stage(0, 0); stage(0, 1); stage(0, 2); stage(0, 3);
  stage(1, 0); stage(1, 2); stage(1, 3);
  vm_wait<6>();                       // tile0 fully landed
  __builtin_amdgcn_s_barrier();

  bf16x8v Ar[4][2], B0r[2][2], B1r[2][2];

  for (int t = 0; t < NT; ++t) {
    const char* buf = lds + ((t & 1) << 16);

    // ---- P0: quadrant (0,0); read A0,B0; stage A1 of t+1
    #pragma unroll
    for (int f = 0; f < 4; ++f)
      #pragma unroll
      for (int kk = 0; kk < 2; ++kk) Ar[f][kk] = rdA(buf, 0, f, kk);
    #pragma unroll
    for (int c = 0; c < 2; ++c)
      #pragma unroll
      for (int kk = 0; kk < 2; ++kk) B0r[c][kk] = rdB(buf, 0, c, kk);
    if (t + 1 < NT) stage(t + 1, 1);
    __builtin_amdgcn_s_barrier();
    LGKM0_FENCE();
    QMFMA(0, 0, B0r);
    __builtin_amdgcn_s_barrier();
    __builtin_amdgcn_sched_barrier(0);

    // ---- P1: quadrant (0,1); read B1; stage A0 of t+2
    #pragma unroll
    for (int c = 0; c < 2; ++c)
      #pragma unroll
      for (int kk = 0; kk < 2; ++kk) B1r[c][kk] = rdB(buf, 1, c, kk);
    if (t + 2 < NT) stage(t + 2, 0);
    __builtin_amdgcn_s_barrier();
    LGKM0_FENCE();
    QMFMA(0, 1, B1r);
    __builtin_amdgcn_s_barrier();
    __builtin_amdgcn_sched_barrier(0);

    // ---- P2: quadrant (1,1); read A1 (overwrite Ar); stage B0 of t+2
    #pragma unroll
    for (int f = 0; f < 4; ++f)
      #pragma unroll
      for (int kk = 0; kk < 2; ++kk) Ar[f][kk] = rdA(buf, 1, f, kk);
    if (t + 2 < NT) stage(t + 2, 2);
    __builtin_amdgcn_s_barrier();
    LGKM0_FENCE();
    QMFMA(1, 1, B1r);
    __builtin_amdgcn_s_barrier();
    __builtin_amdgcn_sched_barrier(0);

    // ---- P3: quadrant (1,0); no reads (A1, B0 resident); stage B1 of t+2
    if (t + 2 < NT) stage(t + 2, 3);
    QMFMA(1, 0, B0r);
    if (t + 2 < NT) vm_wait<6>();     // all of tile t+1 landed; 3 in flight
    else            vm_wait<0>();
    __builtin_amdgcn_s_barrier();
    __builtin_amdgcn_sched_barrier(0);
  }

  // ---- epilogue: C/D layout col=lane&15, row=(lane>>4)*4+reg
  __bf16* Cb = Cmat + (long long)b * cS;
  #pragma unroll
  for (int qa = 0; qa < 2; ++qa) {
    #pragma unroll
    for (int f = 0; f < 4; ++f) {
      const int rrb = m0 + qa * 128 + wm * 64 + f * 16 + lg * 4;
      #pragma unroll
      for (int qb = 0; qb < 2; ++qb) {
        #pragma unroll
        for (int c = 0; c < 2; ++c) {
          const int cc = n0 + qb * 128 + wn * 32 + c * 16 + lr;
          const float cbias = (BIASM == 1) ? bias[cc] : 0.f;
          #pragma unroll
          for (int r = 0; r < 4; ++r) {
            const int rr = rrb + r;
            float v = acc[qa][qb][f][c][r];
            if (BIASM == 1) v += cbias;
            if (BIASM == 2) v += bias[rr];
            Cb[(long long)rr * ldc + cc] = (__bf16)v;
          }
        }
      }
    }
  }
}

// ---------------------------------------------------------------------------
// 2-phase BM x 256 GEMM (kept for the HBM-bound final projection).
// OUTM: 1 = f32 + bias(row) + residual.
// ---------------------------------------------------------------------------
template<int BM, int OUTM, int BIASM>
__global__ __launch_bounds__(512, 2)
void gemm8(const __bf16* __restrict__ Amat, const __bf16* __restrict__ Bmat,
           void* __restrict__ Cmat,
           const float* __restrict__ bias,
           const float* __restrict__ resid,
           int lda, int ldb, int ldc,
           long long aS, long long bS, long long cS, int K)
{
  constexpr int TILE_B = BM * 64 + 16384;
  constexpr int CA = BM / 128;
  constexpr int CH = CA + 2;
  constexpr int FPR = BM / 32;
  constexpr int FPP = FPR / 2;

  __shared__ alignas(16) char lds[3 * TILE_B];

  const int tt = threadIdx.x;
  const int w  = tt >> 6;
  const int l  = tt & 63;
  const int lr = l & 15;
  const int lg = l >> 4;
  const int wm = w >> 2;
  const int wn = w & 3;
  const int b  = blockIdx.z;
  const int n0 = blockIdx.x * 256;
  const int m0 = blockIdx.y * BM;

  const __bf16* Ab = Amat + (long long)b * aS;
  const __bf16* Bb = Bmat + (long long)b * bS;

  const int srow = tt >> 2;
  const int sgr  = (tt & 3) ^ ((tt >> 3) & 3);

  f32x4 acc[FPR][4];
  #pragma unroll
  for (int f = 0; f < FPR; ++f)
    #pragma unroll
    for (int c = 0; c < 4; ++c)
      acc[f][c] = (f32x4){0.f, 0.f, 0.f, 0.f};

  auto stage = [&](int t, int c) {
    const int k0 = t << 5;
    char* dst = lds + (t % 3) * TILE_B + c * 8192 + w * 1024;
    const __bf16* src;
    if (c < CA) src = Ab + (long long)(m0 + c * 128 + srow) * lda + k0 + sgr * 8;
    else        src = Bb + (long long)(n0 + (c - CA) * 128 + srow) * ldb + k0 + sgr * 8;
    gload_lds16(src, dst);
  };
  auto rdA = [&](const char* base, int f) -> bf16x8v {
    const int row = wm * (BM / 2) + f * 16 + lr;
    return *(const bf16x8v*)(base + row * 64 + ((lg ^ ((row >> 1) & 3)) << 4));
  };
  auto rdB = [&](const char* base, int c) -> bf16x8v {
    const int row = wn * 64 + c * 16 + lr;
    return *(const bf16x8v*)(base + BM * 64 + row * 64 + ((lg ^ ((row >> 1) & 3)) << 4));
  };

  const int NT = K >> 5;

  #pragma unroll
  for (int c = 0; c < CH; ++c) stage(0, c);
  #pragma unroll
  for (int c = 0; c < CH; ++c) stage(1, c);

  for (int t = 0; t < NT; ++t) {
    const char* buf = lds + (t % 3) * TILE_B;
    if (t + 1 < NT) vm_wait<CH>();
    else            vm_wait<0>();
    __builtin_amdgcn_s_barrier();
    __builtin_amdgcn_sched_barrier(0);

    bf16x8v Bf[4];
    #pragma unroll
    for (int c = 0; c < 4; ++c) Bf[c] = rdB(buf, c);
    bf16x8v Af[FPP];
    #pragma unroll
    for (int f = 0; f < FPP; ++f) Af[f] = rdA(buf, f);
    if (t + 2 < NT) { stage(t + 2, 0); stage(t + 2, 1); }
    LGKM0_FENCE();
    __builtin_amdgcn_s_setprio(1);
    #pragma unroll
    for (int f = 0; f < FPP; ++f)
      #pragma unroll
      for (int c = 0; c < 4; ++c)
        acc[f][c] = __builtin_amdgcn_mfma_f32_16x16x32_bf16(Af[f], Bf[c], acc[f][c], 0, 0, 0);
    __builtin_amdgcn_s_setprio(0);
    __builtin_amdgcn_s_barrier();
    __builtin_amdgcn_sched_barrier(0);

    bf16x8v Ag[FPP];
    #pragma unroll
    for (int f = 0; f < FPP; ++f) Ag[f] = rdA(buf, FPP + f);
    if (t + 2 < NT) {
      #pragma unroll
      for (int c = 2; c < CH; ++c) stage(t + 2, c);
    }
    LGKM0_FENCE();
    __builtin_amdgcn_s_setprio(1);
    #pragma unroll
    for (int f = 0; f < FPP; ++f)
      #pragma unroll
      for (int c = 0; c < 4; ++c)
        acc[FPP + f][c] = __builtin_amdgcn_mfma_f32_16x16x32_bf16(Ag[f], Bf[c], acc[FPP + f][c], 0, 0, 0);
    __builtin_amdgcn_s_setprio(0);
    __builtin_amdgcn_s_barrier();
    __builtin_amdgcn_sched_barrier(0);
  }

  #pragma unroll
  for (int f = 0; f < FPR; ++f) {
    const int rrb = m0 + wm * (BM / 2) + f * 16 + lg * 4;
    #pragma unroll
    for (int c = 0; c < 4; ++c) {
      const int cc = n0 + wn * 64 + c * 16 + lr;
      const float cbias = (BIASM == 1) ? bias[cc] : 0.f;
      #pragma unroll
      for (int r = 0; r < 4; ++r) {
        const int rr = rrb + r;
        float v = acc[f][c][r];
        if (BIASM == 1) v += cbias;
        if (BIASM == 2) v += bias[rr];
        const long long idx = (long long)rr * ldc + cc;
        if (OUTM == 0) {
          ((__bf16*)Cmat + (long long)b * cS)[idx] = (__bf16)v;
        } else if (OUTM == 2) {
          ((float*)Cmat + (long long)b * cS)[idx] = v;
        } else {
          float* Cf = (float*)Cmat + (long long)b * cS;
          const float* Rf = resid + (long long)b * cS;
          Cf[idx] = v + Rf[idx];
        }
      }
    }
  }
}

// ---------------------------------------------------------------------------
extern "C" void kernel_launch(void* const* d_in, const int* in_sizes, int n_in,
                              void* d_out, int out_size, void* d_ws, size_t ws_size,
                              hipStream_t stream)
{
  const float* x   = (const float*)d_in[0];
  const float* gnw = (const float*)d_in[1];
  const float* gnb = (const float*)d_in[2];
  const float* wq  = (const float*)d_in[3];
  const float* bq  = (const float*)d_in[4];
  const float* wk  = (const float*)d_in[5];
  const float* bk  = (const float*)d_in[6];
  const float* wv  = (const float*)d_in[7];
  const float* bv  = (const float*)d_in[8];
  const float* wo  = (const float*)d_in[9];
  const float* bo  = (const float*)d_in[10];
  (void)in_sizes; (void)n_in; (void)out_size; (void)ws_size;

  size_t used = 0;
  char* base = (char*)d_ws;
  auto carve = [&](size_t bytes) -> void* {
    used = (used + 255) & ~(size_t)255;
    void* p = base + used;
    used += bytes;
    return p;
  };

  __bf16* wqkb = (__bf16*)carve((size_t)2 * C_DIM * C_DIM * 2);
  __bf16* wvb  = (__bf16*)carve((size_t)C_DIM * C_DIM * 2);
  __bf16* wob  = (__bf16*)carve((size_t)C_DIM * C_DIM * 2);
  float*  bqk  = (float*) carve((size_t)1024 * 4);
  float2* part = (float2*)carve((size_t)256 * 8);

  __bf16* hn   = (__bf16*)carve((size_t)16 * HW_N * C_DIM * 2);   // 16MB
  __bf16* qkb  = (__bf16*)carve((size_t)16 * HW_N * 1024 * 2);    // 32MB
  __bf16* vtb  = (__bf16*)carve((size_t)16 * C_DIM * HW_N * 2);   // 16MB
  __bf16* o1b  = (__bf16*)carve((size_t)16 * HW_N * C_DIM * 2);   // 16MB
  __bf16* Sb   = (__bf16*)carve((size_t)16 * HW_N * HW_N * 2);    // 32MB

  const long long sNC = (long long)HW_N * C_DIM;   // 524288
  const long long sNN = (long long)HW_N * 1024;    // 1048576

  prep_kernel<<<dim3(1025), 256, 0, stream>>>(wq, wk, wv, wo, bq, bk,
                                              wqkb, wvb, wob, bqk);
  gn_stats<<<dim3(256), 256, 0, stream>>>(x, part);
  gn_norm<<<dim3(256), 512, 0, stream>>>(x, part, gnw, gnb, hn);

  // qk = hn x Wqk^T + bqk  -> bf16 [B][1024][1024]
  gemm256<1><<<dim3(4, 4, 16), 512, 0, stream>>>(hn, wqkb, qkb, bqk,
      C_DIM, C_DIM, 1024, sNC, 0, sNN, C_DIM);

  // v^T = Wv x hn + bv(row)  -> bf16 [B][512][1024]
  gemm256<2><<<dim3(4, 2, 16), 512, 0, stream>>>(wvb, hn, vtb, bv,
      C_DIM, C_DIM, HW_N, 0, sNC, sNC, C_DIM);

  // S = q x k^T  -> bf16 [B][1024][1024]
  gemm256<0><<<dim3(4, 4, 16), 512, 0, stream>>>(qkb, qkb + 512, Sb, nullptr,
      1024, 1024, 1024, sNN, sNN, sNN, C_DIM);

  // softmax rows, P bf16 in-place
  softmax_kernel<<<dim3(16 * 1024), 256, 0, stream>>>(Sb);

  // O1 = P x V  -> bf16 [B][1024][512]
  gemm256<0><<<dim3(2, 4, 16), 512, 0, stream>>>(Sb, vtb, o1b, nullptr,
      1024, 1024, C_DIM, sNN, sNC, sNC, HW_N);

  // out = Wo x O1^T + bo + x  (fp32 [B][512][1024], residual fused)
  gemm8<128, 1, 2><<<dim3(4, 4, 16), 512, 0, stream>>>(wob, o1b, (float*)d_out, bo, x,
      C_DIM, C_DIM, HW_N, 0, sNC, sNC, C_DIM);
}

// Round 6
// 149.746 us; speedup vs baseline: 1.1268x; 1.1268x over previous
//
#include <hip/hip_runtime.h>
#include <stdint.h>

#define C_DIM 512
#define HW_N  1024
#define CPG   64
#define EPS_GN 1e-5f
#define SCALE_QK 0.044194173824159216f   // 512^-0.5

typedef __attribute__((ext_vector_type(8))) __bf16 bf16x8v;
typedef __attribute__((ext_vector_type(4))) float  f32x4;

typedef __attribute__((address_space(1))) void gvoid_t;
typedef __attribute__((address_space(3))) void lvoid_t;

__device__ __forceinline__ void gload_lds16(const void* g, void* l) {
  __builtin_amdgcn_global_load_lds((gvoid_t*)g, (lvoid_t*)l, 16, 0, 0);
}

__device__ __forceinline__ uint16_t f2bfbits(float f) {
  __bf16 h = (__bf16)f;
  return __builtin_bit_cast(uint16_t, h);
}

__device__ __forceinline__ float bf2f(uint16_t u) {
  return __builtin_bit_cast(float, (uint32_t)u << 16);
}

template<int N>
__device__ __forceinline__ void vm_wait() {
  if constexpr (N == 0)      asm volatile("s_waitcnt vmcnt(0)" ::: "memory");
  else if constexpr (N == 3) asm volatile("s_waitcnt vmcnt(3)" ::: "memory");
  else if constexpr (N == 4) asm volatile("s_waitcnt vmcnt(4)" ::: "memory");
  else if constexpr (N == 6) asm volatile("s_waitcnt vmcnt(6)" ::: "memory");
}

// XCD-bijective block swizzle (nwg must be divisible by 8): blocks resident
// on one XCD get a CONTIGUOUS logical range -> shared operand panels hit the
// same (non-coherent) per-XCD L2. Decode batch-slowest so each XCD owns
// whole batches.
struct BlkId { int bx, by, bz; };
__device__ __forceinline__ BlkId xcd_decode(int gx, int gy) {
  const int nwg = gridDim.x;
  const int bid = blockIdx.x;
  const int wg  = (bid & 7) * (nwg >> 3) + (bid >> 3);
  const int pb  = gx * gy;
  const int bz  = wg / pb;
  const int rem = wg - bz * pb;
  const int by  = rem / gx;
  const int bx  = rem - by * gx;
  return {bx, by, bz};
}

// ---------------------------------------------------------------------------
// GN stats: 256 blocks = (b, g, half). Deterministic fp32 partials.
// ---------------------------------------------------------------------------
__global__ __launch_bounds__(256)
void gn_stats(const float* __restrict__ x, float2* __restrict__ part)
{
  const int lin  = blockIdx.x;
  const int b    = lin >> 4;
  const int g    = (lin >> 1) & 7;
  const int half = lin & 1;
  const int t    = threadIdx.x;

  const float4* xv = (const float4*)(x + ((long long)(b * C_DIM + g * CPG)) * HW_N
                                       + half * 512);
  float s1 = 0.f, s2 = 0.f;
  for (int i = t; i < 64 * 128; i += 256) {
    const int c  = i >> 7;
    const int nf = i & 127;
    float4 v = xv[c * 256 + nf];
    s1 += v.x + v.y + v.z + v.w;
    s2 += v.x * v.x + v.y * v.y + v.z * v.z + v.w * v.w;
  }
  #pragma unroll
  for (int off = 32; off; off >>= 1) {
    s1 += __shfl_xor(s1, off);
    s2 += __shfl_xor(s2, off);
  }
  __shared__ float red[2][4];
  const int w = t >> 6, l = t & 63;
  if (l == 0) { red[0][w] = s1; red[1][w] = s2; }
  __syncthreads();
  if (t == 0) {
    s1 = red[0][0] + red[0][1] + red[0][2] + red[0][3];
    s2 = red[1][0] + red[1][1] + red[1][2] + red[1][3];
    part[lin] = make_float2(s1, s2);
  }
}

// ---------------------------------------------------------------------------
// GN normalize + transpose -> hn^T bf16 [N][C], bf16x8 stores.
// ---------------------------------------------------------------------------
__global__ __launch_bounds__(512)
void gn_norm(const float* __restrict__ x, const float2* __restrict__ part,
             const float* __restrict__ gnw, const float* __restrict__ gnb,
             __bf16* __restrict__ hn)
{
  const int b  = blockIdx.x >> 4;
  const int nc = blockIdx.x & 15;
  const int t  = threadIdx.x;

  __shared__ float asc[512], bsc[512];
  __shared__ float tile[64][65];

  {
    const int c = t;
    const int g = c >> 6;
    float2 p0 = part[(b * 8 + g) * 2 + 0];
    float2 p1 = part[(b * 8 + g) * 2 + 1];
    const float mean = (p0.x + p1.x) * (1.f / 65536.f);
    const float var  = (p0.y + p1.y) * (1.f / 65536.f) - mean * mean;
    const float rstd = rsqrtf(var + EPS_GN);
    const float a = rstd * gnw[c];
    asc[c] = a;
    bsc[c] = gnb[c] - mean * a;
  }
  __syncthreads();

  const long long xb = (long long)b * C_DIM * HW_N + nc * 64;
  __bf16* ob = hn + ((long long)b * HW_N + nc * 64) * C_DIM;

  for (int cg = 0; cg < 8; ++cg) {
    #pragma unroll
    for (int pass = 0; pass < 2; ++pass) {
      const int task = pass * 512 + t;
      const int c  = task >> 4;
      const int f4 = task & 15;
      float4 v = *(const float4*)(x + xb + (long long)(cg * 64 + c) * HW_N + f4 * 4);
      const float a  = asc[cg * 64 + c];
      const float bb = bsc[cg * 64 + c];
      tile[c][f4 * 4 + 0] = v.x * a + bb;
      tile[c][f4 * 4 + 1] = v.y * a + bb;
      tile[c][f4 * 4 + 2] = v.z * a + bb;
      tile[c][f4 * 4 + 3] = v.w * a + bb;
    }
    __syncthreads();
    {
      const int n  = t >> 3;
      const int gc = t & 7;
      uint32_t p[4];
      #pragma unroll
      for (int j = 0; j < 4; ++j) {
        const float f0 = tile[gc * 8 + 2 * j + 0][n];
        const float f1 = tile[gc * 8 + 2 * j + 1][n];
        p[j] = (uint32_t)f2bfbits(f0) | ((uint32_t)f2bfbits(f1) << 16);
      }
      *(uint4*)(ob + (long long)n * C_DIM + cg * 64 + gc * 8) =
          make_uint4(p[0], p[1], p[2], p[3]);
    }
    __syncthreads();
  }
}

// ---------------------------------------------------------------------------
// Prep: 4 weight conversions (+scale fold on Wq) + bias concat.
// ---------------------------------------------------------------------------
__global__ __launch_bounds__(256)
void prep_kernel(const float* __restrict__ wq, const float* __restrict__ wk,
                 const float* __restrict__ wv, const float* __restrict__ wo,
                 const float* __restrict__ bq, const float* __restrict__ bk,
                 __bf16* __restrict__ wqkb, __bf16* __restrict__ wvb,
                 __bf16* __restrict__ wob, float* __restrict__ bqk)
{
  const int blk = blockIdx.x;
  if (blk < 1024) {
    const int which = blk >> 8;
    const int i = (blk & 255) * 256 + threadIdx.x;
    const float* src = (which == 0) ? wq : (which == 1) ? wk : (which == 2) ? wv : wo;
    __bf16* dst = (which == 0) ? wqkb
               : (which == 1) ? (wqkb + (size_t)C_DIM * C_DIM)
               : (which == 2) ? wvb : wob;
    const float scale = (which == 0) ? SCALE_QK : 1.f;
    float4 v = ((const float4*)src)[i];
    uint32_t lo = (uint32_t)f2bfbits(v.x * scale) | ((uint32_t)f2bfbits(v.y * scale) << 16);
    uint32_t hi = (uint32_t)f2bfbits(v.z * scale) | ((uint32_t)f2bfbits(v.w * scale) << 16);
    ((uint2*)dst)[i] = make_uint2(lo, hi);
  } else {
    for (int j = threadIdx.x; j < 1024; j += 256)
      bqk[j] = (j < 512) ? bq[j] * SCALE_QK : bk[j - 512];
  }
}

// ---------------------------------------------------------------------------
// Row softmax over bf16 S [rows][1024], in-place -> bf16 P.
// ---------------------------------------------------------------------------
__global__ __launch_bounds__(256)
void softmax_kernel(__bf16* __restrict__ S)
{
  const long long row = blockIdx.x;
  uint2* sp = (uint2*)(S + row * HW_N);
  const int t = threadIdx.x;
  uint2 raw = sp[t];
  float v0 = bf2f((uint16_t)(raw.x & 0xffff));
  float v1 = bf2f((uint16_t)(raw.x >> 16));
  float v2 = bf2f((uint16_t)(raw.y & 0xffff));
  float v3 = bf2f((uint16_t)(raw.y >> 16));
  float m = fmaxf(fmaxf(v0, v1), fmaxf(v2, v3));
  #pragma unroll
  for (int off = 32; off; off >>= 1) m = fmaxf(m, __shfl_xor(m, off));
  __shared__ float redm[4];
  __shared__ float reds[4];
  const int w = t >> 6, l = t & 63;
  if (l == 0) redm[w] = m;
  __syncthreads();
  m = fmaxf(fmaxf(redm[0], redm[1]), fmaxf(redm[2], redm[3]));
  float e0 = __expf(v0 - m), e1 = __expf(v1 - m);
  float e2 = __expf(v2 - m), e3 = __expf(v3 - m);
  float sum = e0 + e1 + e2 + e3;
  #pragma unroll
  for (int off = 32; off; off >>= 1) sum += __shfl_xor(sum, off);
  if (l == 0) reds[w] = sum;
  __syncthreads();
  sum = reds[0] + reds[1] + reds[2] + reds[3];
  const float inv = 1.f / sum;
  uint32_t lo = (uint32_t)f2bfbits(e0 * inv) | ((uint32_t)f2bfbits(e1 * inv) << 16);
  uint32_t hi = (uint32_t)f2bfbits(e2 * inv) | ((uint32_t)f2bfbits(e3 * inv) << 16);
  sp[t] = make_uint2(lo, hi);
}

// ---------------------------------------------------------------------------
// 8-phase 256x256 bf16 GEMM (m201-style), 1D grid + XCD swizzle.
// C[M][N] = A[M][K] x B[N][K]^T. BIASM: 0 none, 1 per-col, 2 per-row.
// ---------------------------------------------------------------------------
#define QMFMA(QA, QB, BREG)                                                    \
  do {                                                                         \
    __builtin_amdgcn_s_setprio(1);                                             \
    _Pragma("unroll")                                                          \
    for (int f_ = 0; f_ < 4; ++f_)                                             \
      _Pragma("unroll")                                                        \
      for (int c_ = 0; c_ < 2; ++c_)                                           \
        _Pragma("unroll")                                                      \
        for (int kk_ = 0; kk_ < 2; ++kk_)                                      \
          acc[QA][QB][f_][c_] = __builtin_amdgcn_mfma_f32_16x16x32_bf16(       \
              Ar[f_][kk_], BREG[c_][kk_], acc[QA][QB][f_][c_], 0, 0, 0);       \
    __builtin_amdgcn_s_setprio(0);                                             \
  } while (0)

#define LGKM0_FENCE()                                                          \
  asm volatile("s_waitcnt lgkmcnt(0)" ::: "memory");                           \
  __builtin_amdgcn_sched_barrier(0)

template<int BIASM>
__global__ __launch_bounds__(512, 2)
void gemm256(const __bf16* __restrict__ Amat, const __bf16* __restrict__ Bmat,
             __bf16* __restrict__ Cmat, const float* __restrict__ bias,
             int lda, int ldb, int ldc,
             long long aS, long long bS, long long cS, int K, int gx, int gy)
{
  __shared__ alignas(16) char lds[131072];   // 2 buf x [A0|A1|B0|B1] x 16KB

  const int tt = threadIdx.x;
  const int w  = tt >> 6;
  const int l  = tt & 63;
  const int lr = l & 15;
  const int lg = l >> 4;
  const int wm = w >> 2;      // 0..1
  const int wn = w & 3;       // 0..3
  const BlkId bk_ = xcd_decode(gx, gy);
  const int b  = bk_.bz;
  const int n0 = bk_.bx * 256;
  const int m0 = bk_.by * 256;

  const __bf16* Ab = Amat + (long long)b * aS;
  const __bf16* Bb = Bmat + (long long)b * bS;

  const int r0  = tt >> 3;
  const int sg8 = ((tt & 7) ^ ((tt >> 3) & 7)) << 3;

  f32x4 acc[2][2][4][2];
  #pragma unroll
  for (int qa = 0; qa < 2; ++qa)
    #pragma unroll
    for (int qb = 0; qb < 2; ++qb)
      #pragma unroll
      for (int f = 0; f < 4; ++f)
        #pragma unroll
        for (int c = 0; c < 2; ++c)
          acc[qa][qb][f][c] = (f32x4){0.f, 0.f, 0.f, 0.f};

  auto stage = [&](int kt, int h) {   // h: 0=A0 1=A1 2=B0 3=B1
    char* dst = lds + ((kt & 1) << 16) + (h << 14) + w * 1024;
    const long long ld = (h < 2) ? lda : ldb;
    const __bf16* src = ((h < 2) ? Ab + (long long)(m0 + (h & 1) * 128) * lda
                                 : Bb + (long long)(n0 + (h & 1) * 128) * ldb)
                        + (long long)kt * 64 + sg8;
    gload_lds16(src + (long long)r0 * ld, dst);
    gload_lds16(src + (long long)(r0 + 64) * ld, dst + 8192);
  };
  auto rdA = [&](const char* bb, int qa, int f, int kk) -> bf16x8v {
    const int r = wm * 64 + f * 16 + lr;
    return *(const bf16x8v*)(bb + (qa << 14) + r * 128
                             + (((kk * 4 + lg) ^ (r & 7)) << 4));
  };
  auto rdB = [&](const char* bb, int qb, int c, int kk) -> bf16x8v {
    const int r = wn * 32 + c * 16 + lr;
    return *(const bf16x8v*)(bb + 32768 + (qb << 14) + r * 128
                             + (((kk * 4 + lg) ^ (r & 7)) << 4));
  };

  const int NT = K >> 6;

  stage(0, 0); stage(0, 1); stage(0, 2); stage(0, 3);
  stage(1, 0); stage(1, 2); stage(1, 3);
  vm_wait<6>();
  __builtin_amdgcn_s_barrier();

  bf16x8v Ar[4][2], B0r[2][2], B1r[2][2];

  for (int t = 0; t < NT; ++t) {
    const char* buf = lds + ((t & 1) << 16);

    // ---- P0: quadrant (0,0); read A0,B0; stage A1 of t+1
    #pragma unroll
    for (int f = 0; f < 4; ++f)
      #pragma unroll
      for (int kk = 0; kk < 2; ++kk) Ar[f][kk] = rdA(buf, 0, f, kk);
    #pragma unroll
    for (int c = 0; c < 2; ++c)
      #pragma unroll
      for (int kk = 0; kk < 2; ++kk) B0r[c][kk] = rdB(buf, 0, c, kk);
    if (t + 1 < NT) stage(t + 1, 1);
    __builtin_amdgcn_s_barrier();
    LGKM0_FENCE();
    QMFMA(0, 0, B0r);
    __builtin_amdgcn_s_barrier();
    __builtin_amdgcn_sched_barrier(0);

    // ---- P1: quadrant (0,1); read B1; stage A0 of t+2
    #pragma unroll
    for (int c = 0; c < 2; ++c)
      #pragma unroll
      for (int kk = 0; kk < 2; ++kk) B1r[c][kk] = rdB(buf, 1, c, kk);
    if (t + 2 < NT) stage(t + 2, 0);
    __builtin_amdgcn_s_barrier();
    LGKM0_FENCE();
    QMFMA(0, 1, B1r);
    __builtin_amdgcn_s_barrier();
    __builtin_amdgcn_sched_barrier(0);

    // ---- P2: quadrant (1,1); read A1; stage B0 of t+2
    #pragma unroll
    for (int f = 0; f < 4; ++f)
      #pragma unroll
      for (int kk = 0; kk < 2; ++kk) Ar[f][kk] = rdA(buf, 1, f, kk);
    if (t + 2 < NT) stage(t + 2, 2);
    __builtin_amdgcn_s_barrier();
    LGKM0_FENCE();
    QMFMA(1, 1, B1r);
    __builtin_amdgcn_s_barrier();
    __builtin_amdgcn_sched_barrier(0);

    // ---- P3: quadrant (1,0); stage B1 of t+2; ONE counted vmcnt per tile
    if (t + 2 < NT) stage(t + 2, 3);
    QMFMA(1, 0, B0r);
    if (t + 2 < NT) vm_wait<6>();
    else            vm_wait<0>();
    __builtin_amdgcn_s_barrier();
    __builtin_amdgcn_sched_barrier(0);
  }

  __bf16* Cb = Cmat + (long long)b * cS;
  #pragma unroll
  for (int qa = 0; qa < 2; ++qa) {
    #pragma unroll
    for (int f = 0; f < 4; ++f) {
      const int rrb = m0 + qa * 128 + wm * 64 + f * 16 + lg * 4;
      #pragma unroll
      for (int qb = 0; qb < 2; ++qb) {
        #pragma unroll
        for (int c = 0; c < 2; ++c) {
          const int cc = n0 + qb * 128 + wn * 32 + c * 16 + lr;
          const float cbias = (BIASM == 1) ? bias[cc] : 0.f;
          #pragma unroll
          for (int r = 0; r < 4; ++r) {
            const int rr = rrb + r;
            float v = acc[qa][qb][f][c][r];
            if (BIASM == 1) v += cbias;
            if (BIASM == 2) v += bias[rr];
            Cb[(long long)rr * ldc + cc] = (__bf16)v;
          }
        }
      }
    }
  }
}

// ---------------------------------------------------------------------------
// 2-phase BM x 256 GEMM, 1D grid + XCD swizzle (2 blocks/CU at BM=128).
// OUTM: 0=bf16, 1=f32+bias+residual, 2=f32. BIASM: 0 none, 1 col, 2 row.
// ---------------------------------------------------------------------------
template<int BM, int OUTM, int BIASM>
__global__ __launch_bounds__(512, 2)
void gemm8(const __bf16* __restrict__ Amat, const __bf16* __restrict__ Bmat,
           void* __restrict__ Cmat,
           const float* __restrict__ bias,
           const float* __restrict__ resid,
           int lda, int ldb, int ldc,
           long long aS, long long bS, long long cS, int K, int gx, int gy)
{
  constexpr int TILE_B = BM * 64 + 16384;
  constexpr int CA = BM / 128;
  constexpr int CH = CA + 2;
  constexpr int FPR = BM / 32;
  constexpr int FPP = FPR / 2;

  __shared__ alignas(16) char lds[3 * TILE_B];

  const int tt = threadIdx.x;
  const int w  = tt >> 6;
  const int l  = tt & 63;
  const int lr = l & 15;
  const int lg = l >> 4;
  const int wm = w >> 2;
  const int wn = w & 3;
  const BlkId bk_ = xcd_decode(gx, gy);
  const int b  = bk_.bz;
  const int n0 = bk_.bx * 256;
  const int m0 = bk_.by * BM;

  const __bf16* Ab = Amat + (long long)b * aS;
  const __bf16* Bb = Bmat + (long long)b * bS;

  const int srow = tt >> 2;
  const int sgr  = (tt & 3) ^ ((tt >> 3) & 3);

  f32x4 acc[FPR][4];
  #pragma unroll
  for (int f = 0; f < FPR; ++f)
    #pragma unroll
    for (int c = 0; c < 4; ++c)
      acc[f][c] = (f32x4){0.f, 0.f, 0.f, 0.f};

  auto stage = [&](int t, int c) {
    const int k0 = t << 5;
    char* dst = lds + (t % 3) * TILE_B + c * 8192 + w * 1024;
    const __bf16* src;
    if (c < CA) src = Ab + (long long)(m0 + c * 128 + srow) * lda + k0 + sgr * 8;
    else        src = Bb + (long long)(n0 + (c - CA) * 128 + srow) * ldb + k0 + sgr * 8;
    gload_lds16(src, dst);
  };
  auto rdA = [&](const char* base, int f) -> bf16x8v {
    const int row = wm * (BM / 2) + f * 16 + lr;
    return *(const bf16x8v*)(base + row * 64 + ((lg ^ ((row >> 1) & 3)) << 4));
  };
  auto rdB = [&](const char* base, int c) -> bf16x8v {
    const int row = wn * 64 + c * 16 + lr;
    return *(const bf16x8v*)(base + BM * 64 + row * 64 + ((lg ^ ((row >> 1) & 3)) << 4));
  };

  const int NT = K >> 5;

  #pragma unroll
  for (int c = 0; c < CH; ++c) stage(0, c);
  #pragma unroll
  for (int c = 0; c < CH; ++c) stage(1, c);

  for (int t = 0; t < NT; ++t) {
    const char* buf = lds + (t % 3) * TILE_B;
    if (t + 1 < NT) vm_wait<CH>();
    else            vm_wait<0>();
    __builtin_amdgcn_s_barrier();
    __builtin_amdgcn_sched_barrier(0);

    bf16x8v Bf[4];
    #pragma unroll
    for (int c = 0; c < 4; ++c) Bf[c] = rdB(buf, c);
    bf16x8v Af[FPP];
    #pragma unroll
    for (int f = 0; f < FPP; ++f) Af[f] = rdA(buf, f);
    if (t + 2 < NT) { stage(t + 2, 0); stage(t + 2, 1); }
    LGKM0_FENCE();
    __builtin_amdgcn_s_setprio(1);
    #pragma unroll
    for (int f = 0; f < FPP; ++f)
      #pragma unroll
      for (int c = 0; c < 4; ++c)
        acc[f][c] = __builtin_amdgcn_mfma_f32_16x16x32_bf16(Af[f], Bf[c], acc[f][c], 0, 0, 0);
    __builtin_amdgcn_s_setprio(0);
    __builtin_amdgcn_s_barrier();
    __builtin_amdgcn_sched_barrier(0);

    bf16x8v Ag[FPP];
    #pragma unroll
    for (int f = 0; f < FPP; ++f) Ag[f] = rdA(buf, FPP + f);
    if (t + 2 < NT) {
      #pragma unroll
      for (int c = 2; c < CH; ++c) stage(t + 2, c);
    }
    LGKM0_FENCE();
    __builtin_amdgcn_s_setprio(1);
    #pragma unroll
    for (int f = 0; f < FPP; ++f)
      #pragma unroll
      for (int c = 0; c < 4; ++c)
        acc[FPP + f][c] = __builtin_amdgcn_mfma_f32_16x16x32_bf16(Ag[f], Bf[c], acc[FPP + f][c], 0, 0, 0);
    __builtin_amdgcn_s_setprio(0);
    __builtin_amdgcn_s_barrier();
    __builtin_amdgcn_sched_barrier(0);
  }

  #pragma unroll
  for (int f = 0; f < FPR; ++f) {
    const int rrb = m0 + wm * (BM / 2) + f * 16 + lg * 4;
    #pragma unroll
    for (int c = 0; c < 4; ++c) {
      const int cc = n0 + wn * 64 + c * 16 + lr;
      const float cbias = (BIASM == 1) ? bias[cc] : 0.f;
      #pragma unroll
      for (int r = 0; r < 4; ++r) {
        const int rr = rrb + r;
        float v = acc[f][c][r];
        if (BIASM == 1) v += cbias;
        if (BIASM == 2) v += bias[rr];
        const long long idx = (long long)rr * ldc + cc;
        if (OUTM == 0) {
          ((__bf16*)Cmat + (long long)b * cS)[idx] = (__bf16)v;
        } else if (OUTM == 2) {
          ((float*)Cmat + (long long)b * cS)[idx] = v;
        } else {
          float* Cf = (float*)Cmat + (long long)b * cS;
          const float* Rf = resid + (long long)b * cS;
          Cf[idx] = v + Rf[idx];
        }
      }
    }
  }
}

// ---------------------------------------------------------------------------
extern "C" void kernel_launch(void* const* d_in, const int* in_sizes, int n_in,
                              void* d_out, int out_size, void* d_ws, size_t ws_size,
                              hipStream_t stream)
{
  const float* x   = (const float*)d_in[0];
  const float* gnw = (const float*)d_in[1];
  const float* gnb = (const float*)d_in[2];
  const float* wq  = (const float*)d_in[3];
  const float* bq  = (const float*)d_in[4];
  const float* wk  = (const float*)d_in[5];
  const float* bk  = (const float*)d_in[6];
  const float* wv  = (const float*)d_in[7];
  const float* bv  = (const float*)d_in[8];
  const float* wo  = (const float*)d_in[9];
  const float* bo  = (const float*)d_in[10];
  (void)in_sizes; (void)n_in; (void)out_size; (void)ws_size;

  size_t used = 0;
  char* base = (char*)d_ws;
  auto carve = [&](size_t bytes) -> void* {
    used = (used + 255) & ~(size_t)255;
    void* p = base + used;
    used += bytes;
    return p;
  };

  __bf16* wqkb = (__bf16*)carve((size_t)2 * C_DIM * C_DIM * 2);
  __bf16* wvb  = (__bf16*)carve((size_t)C_DIM * C_DIM * 2);
  __bf16* wob  = (__bf16*)carve((size_t)C_DIM * C_DIM * 2);
  float*  bqk  = (float*) carve((size_t)1024 * 4);
  float2* part = (float2*)carve((size_t)256 * 8);

  __bf16* hn   = (__bf16*)carve((size_t)16 * HW_N * C_DIM * 2);   // 16MB
  __bf16* qkb  = (__bf16*)carve((size_t)16 * HW_N * 1024 * 2);    // 32MB
  __bf16* vtb  = (__bf16*)carve((size_t)16 * C_DIM * HW_N * 2);   // 16MB
  __bf16* o1b  = (__bf16*)carve((size_t)16 * HW_N * C_DIM * 2);   // 16MB
  __bf16* Sb   = (__bf16*)carve((size_t)16 * HW_N * HW_N * 2);    // 32MB

  const long long sNC = (long long)HW_N * C_DIM;   // 524288
  const long long sNN = (long long)HW_N * 1024;    // 1048576

  prep_kernel<<<dim3(1025), 256, 0, stream>>>(wq, wk, wv, wo, bq, bk,
                                              wqkb, wvb, wob, bqk);
  gn_stats<<<dim3(256), 256, 0, stream>>>(x, part);
  gn_norm<<<dim3(256), 512, 0, stream>>>(x, part, gnw, gnb, hn);

  // qk = hn x Wqk^T + bqk  -> bf16 [B][1024][1024]  (8-phase, 256 blocks)
  gemm256<1><<<dim3(256), 512, 0, stream>>>(hn, wqkb, qkb, bqk,
      C_DIM, C_DIM, 1024, sNC, 0, sNN, C_DIM, 4, 4);

  // v^T = Wv x hn + bv(row) -> bf16 [B][512][1024]  (2-phase, 256 blocks)
  gemm8<128, 0, 2><<<dim3(256), 512, 0, stream>>>(wvb, hn, vtb, bv, nullptr,
      C_DIM, C_DIM, HW_N, 0, sNC, sNC, C_DIM, 4, 4);

  // S = q x k^T -> bf16 [B][1024][1024]  (8-phase, 256 blocks)
  gemm256<0><<<dim3(256), 512, 0, stream>>>(qkb, qkb + 512, Sb, nullptr,
      1024, 1024, 1024, sNN, sNN, sNN, C_DIM, 4, 4);

  // softmax rows, P bf16 in-place
  softmax_kernel<<<dim3(16 * 1024), 256, 0, stream>>>(Sb);

  // O1 = P x V -> bf16 [B][1024][512]  (2-phase, 256 blocks)
  gemm8<128, 0, 0><<<dim3(256), 512, 0, stream>>>(Sb, vtb, o1b, nullptr, nullptr,
      1024, 1024, C_DIM, sNN, sNC, sNC, HW_N, 2, 8);

  // out = Wo x O1^T + bo + x  (fp32 [B][512][1024], residual fused)
  gemm8<128, 1, 2><<<dim3(256), 512, 0, stream>>>(wob, o1b, (float*)d_out, bo, x,
      C_DIM, C_DIM, HW_N, 0, sNC, sNC, C_DIM, 4, 4);
}

// Round 7
// 149.597 us; speedup vs baseline: 1.1279x; 1.0010x over previous
//
#include <hip/hip_runtime.h>
#include <stdint.h>

#define C_DIM 512
#define HW_N  1024
#define CPG   64
#define EPS_GN 1e-5f
#define SCALE_QK 0.044194173824159216f   // 512^-0.5

typedef __attribute__((ext_vector_type(8))) __bf16 bf16x8v;
typedef __attribute__((ext_vector_type(4))) float  f32x4;

typedef __attribute__((address_space(1))) void gvoid_t;
typedef __attribute__((address_space(3))) void lvoid_t;

__device__ __forceinline__ void gload_lds16(const void* g, void* l) {
  __builtin_amdgcn_global_load_lds((gvoid_t*)g, (lvoid_t*)l, 16, 0, 0);
}

__device__ __forceinline__ uint16_t f2bfbits(float f) {
  __bf16 h = (__bf16)f;
  return __builtin_bit_cast(uint16_t, h);
}

__device__ __forceinline__ float bf2f(uint16_t u) {
  return __builtin_bit_cast(float, (uint32_t)u << 16);
}

template<int N>
__device__ __forceinline__ void vm_wait() {
  if constexpr (N == 0)      asm volatile("s_waitcnt vmcnt(0)" ::: "memory");
  else if constexpr (N == 3) asm volatile("s_waitcnt vmcnt(3)" ::: "memory");
  else if constexpr (N == 4) asm volatile("s_waitcnt vmcnt(4)" ::: "memory");
  else if constexpr (N == 6) asm volatile("s_waitcnt vmcnt(6)" ::: "memory");
}

#define LGKM0_FENCE()                                                          \
  asm volatile("s_waitcnt lgkmcnt(0)" ::: "memory");                           \
  __builtin_amdgcn_sched_barrier(0)

// XCD-bijective block swizzle (nwg divisible by 8): each XCD gets a
// contiguous logical range -> shared panels hit the same per-XCD L2.
struct BlkId { int bx, by, bz; };
__device__ __forceinline__ BlkId xcd_decode(int gx, int gy) {
  const int nwg = gridDim.x;
  const int bid = blockIdx.x;
  const int wg  = (bid & 7) * (nwg >> 3) + (bid >> 3);
  const int pb  = gx * gy;
  const int bz  = wg / pb;
  const int rem = wg - bz * pb;
  const int by  = rem / gx;
  const int bx  = rem - by * gx;
  return {bx, by, bz};
}

// ---------------------------------------------------------------------------
// GN stats: 256 blocks = (b, g, half). Deterministic fp32 partials.
// ---------------------------------------------------------------------------
__global__ __launch_bounds__(256)
void gn_stats(const float* __restrict__ x, float2* __restrict__ part)
{
  const int lin  = blockIdx.x;
  const int b    = lin >> 4;
  const int g    = (lin >> 1) & 7;
  const int half = lin & 1;
  const int t    = threadIdx.x;

  const float4* xv = (const float4*)(x + ((long long)(b * C_DIM + g * CPG)) * HW_N
                                       + half * 512);
  float s1 = 0.f, s2 = 0.f;
  for (int i = t; i < 64 * 128; i += 256) {
    const int c  = i >> 7;
    const int nf = i & 127;
    float4 v = xv[c * 256 + nf];
    s1 += v.x + v.y + v.z + v.w;
    s2 += v.x * v.x + v.y * v.y + v.z * v.z + v.w * v.w;
  }
  #pragma unroll
  for (int off = 32; off; off >>= 1) {
    s1 += __shfl_xor(s1, off);
    s2 += __shfl_xor(s2, off);
  }
  __shared__ float red[2][4];
  const int w = t >> 6, l = t & 63;
  if (l == 0) { red[0][w] = s1; red[1][w] = s2; }
  __syncthreads();
  if (t == 0) {
    s1 = red[0][0] + red[0][1] + red[0][2] + red[0][3];
    s2 = red[1][0] + red[1][1] + red[1][2] + red[1][3];
    part[lin] = make_float2(s1, s2);
  }
}

// ---------------------------------------------------------------------------
// GN normalize + transpose -> hn^T bf16 [N][C], bf16x8 stores.
// ---------------------------------------------------------------------------
__global__ __launch_bounds__(512)
void gn_norm(const float* __restrict__ x, const float2* __restrict__ part,
             const float* __restrict__ gnw, const float* __restrict__ gnb,
             __bf16* __restrict__ hn)
{
  const int b  = blockIdx.x >> 4;
  const int nc = blockIdx.x & 15;
  const int t  = threadIdx.x;

  __shared__ float asc[512], bsc[512];
  __shared__ float tile[64][65];

  {
    const int c = t;
    const int g = c >> 6;
    float2 p0 = part[(b * 8 + g) * 2 + 0];
    float2 p1 = part[(b * 8 + g) * 2 + 1];
    const float mean = (p0.x + p1.x) * (1.f / 65536.f);
    const float var  = (p0.y + p1.y) * (1.f / 65536.f) - mean * mean;
    const float rstd = rsqrtf(var + EPS_GN);
    const float a = rstd * gnw[c];
    asc[c] = a;
    bsc[c] = gnb[c] - mean * a;
  }
  __syncthreads();

  const long long xb = (long long)b * C_DIM * HW_N + nc * 64;
  __bf16* ob = hn + ((long long)b * HW_N + nc * 64) * C_DIM;

  for (int cg = 0; cg < 8; ++cg) {
    #pragma unroll
    for (int pass = 0; pass < 2; ++pass) {
      const int task = pass * 512 + t;
      const int c  = task >> 4;
      const int f4 = task & 15;
      float4 v = *(const float4*)(x + xb + (long long)(cg * 64 + c) * HW_N + f4 * 4);
      const float a  = asc[cg * 64 + c];
      const float bb = bsc[cg * 64 + c];
      tile[c][f4 * 4 + 0] = v.x * a + bb;
      tile[c][f4 * 4 + 1] = v.y * a + bb;
      tile[c][f4 * 4 + 2] = v.z * a + bb;
      tile[c][f4 * 4 + 3] = v.w * a + bb;
    }
    __syncthreads();
    {
      const int n  = t >> 3;
      const int gc = t & 7;
      uint32_t p[4];
      #pragma unroll
      for (int j = 0; j < 4; ++j) {
        const float f0 = tile[gc * 8 + 2 * j + 0][n];
        const float f1 = tile[gc * 8 + 2 * j + 1][n];
        p[j] = (uint32_t)f2bfbits(f0) | ((uint32_t)f2bfbits(f1) << 16);
      }
      *(uint4*)(ob + (long long)n * C_DIM + cg * 64 + gc * 8) =
          make_uint4(p[0], p[1], p[2], p[3]);
    }
    __syncthreads();
  }
}

// ---------------------------------------------------------------------------
// Prep: 4 weight conversions (+scale fold on Wq) + bias concat.
// ---------------------------------------------------------------------------
__global__ __launch_bounds__(256)
void prep_kernel(const float* __restrict__ wq, const float* __restrict__ wk,
                 const float* __restrict__ wv, const float* __restrict__ wo,
                 const float* __restrict__ bq, const float* __restrict__ bk,
                 __bf16* __restrict__ wqkb, __bf16* __restrict__ wvb,
                 __bf16* __restrict__ wob, float* __restrict__ bqk)
{
  const int blk = blockIdx.x;
  if (blk < 1024) {
    const int which = blk >> 8;
    const int i = (blk & 255) * 256 + threadIdx.x;
    const float* src = (which == 0) ? wq : (which == 1) ? wk : (which == 2) ? wv : wo;
    __bf16* dst = (which == 0) ? wqkb
               : (which == 1) ? (wqkb + (size_t)C_DIM * C_DIM)
               : (which == 2) ? wvb : wob;
    const float scale = (which == 0) ? SCALE_QK : 1.f;
    float4 v = ((const float4*)src)[i];
    uint32_t lo = (uint32_t)f2bfbits(v.x * scale) | ((uint32_t)f2bfbits(v.y * scale) << 16);
    uint32_t hi = (uint32_t)f2bfbits(v.z * scale) | ((uint32_t)f2bfbits(v.w * scale) << 16);
    ((uint2*)dst)[i] = make_uint2(lo, hi);
  } else {
    for (int j = threadIdx.x; j < 1024; j += 256)
      bqk[j] = (j < 512) ? bq[j] * SCALE_QK : bk[j - 512];
  }
}

// ---------------------------------------------------------------------------
// Row softmax over bf16 S [rows][1024], in-place -> bf16 P.
// ---------------------------------------------------------------------------
__global__ __launch_bounds__(256)
void softmax_kernel(__bf16* __restrict__ S)
{
  const long long row = blockIdx.x;
  uint2* sp = (uint2*)(S + row * HW_N);
  const int t = threadIdx.x;
  uint2 raw = sp[t];
  float v0 = bf2f((uint16_t)(raw.x & 0xffff));
  float v1 = bf2f((uint16_t)(raw.x >> 16));
  float v2 = bf2f((uint16_t)(raw.y & 0xffff));
  float v3 = bf2f((uint16_t)(raw.y >> 16));
  float m = fmaxf(fmaxf(v0, v1), fmaxf(v2, v3));
  #pragma unroll
  for (int off = 32; off; off >>= 1) m = fmaxf(m, __shfl_xor(m, off));
  __shared__ float redm[4];
  __shared__ float reds[4];
  const int w = t >> 6, l = t & 63;
  if (l == 0) redm[w] = m;
  __syncthreads();
  m = fmaxf(fmaxf(redm[0], redm[1]), fmaxf(redm[2], redm[3]));
  float e0 = __expf(v0 - m), e1 = __expf(v1 - m);
  float e2 = __expf(v2 - m), e3 = __expf(v3 - m);
  float sum = e0 + e1 + e2 + e3;
  #pragma unroll
  for (int off = 32; off; off >>= 1) sum += __shfl_xor(sum, off);
  if (l == 0) reds[w] = sum;
  __syncthreads();
  sum = reds[0] + reds[1] + reds[2] + reds[3];
  const float inv = 1.f / sum;
  uint32_t lo = (uint32_t)f2bfbits(e0 * inv) | ((uint32_t)f2bfbits(e1 * inv) << 16);
  uint32_t hi = (uint32_t)f2bfbits(e2 * inv) | ((uint32_t)f2bfbits(e3 * inv) << 16);
  sp[t] = make_uint2(lo, hi);
}

// ---------------------------------------------------------------------------
// 2-phase BM x 256 GEMM, 1D grid + XCD swizzle. BM=128 -> 72KB LDS ->
// 2 blocks/CU when the grid has 512 blocks (latency hiding across blocks).
// OUTM: 0=bf16, 1=f32+bias+residual, 2=f32. BIASM: 0 none, 1 col, 2 row.
// ---------------------------------------------------------------------------
template<int BM, int OUTM, int BIASM>
__global__ __launch_bounds__(512, 2)
void gemm8(const __bf16* __restrict__ Amat, const __bf16* __restrict__ Bmat,
           void* __restrict__ Cmat,
           const float* __restrict__ bias,
           const float* __restrict__ resid,
           int lda, int ldb, int ldc,
           long long aS, long long bS, long long cS, int K, int gx, int gy)
{
  constexpr int TILE_B = BM * 64 + 16384;
  constexpr int CA = BM / 128;
  constexpr int CH = CA + 2;
  constexpr int FPR = BM / 32;
  constexpr int FPP = FPR / 2;

  __shared__ alignas(16) char lds[3 * TILE_B];

  const int tt = threadIdx.x;
  const int w  = tt >> 6;
  const int l  = tt & 63;
  const int lr = l & 15;
  const int lg = l >> 4;
  const int wm = w >> 2;
  const int wn = w & 3;
  const BlkId bk_ = xcd_decode(gx, gy);
  const int b  = bk_.bz;
  const int n0 = bk_.bx * 256;
  const int m0 = bk_.by * BM;

  const __bf16* Ab = Amat + (long long)b * aS;
  const __bf16* Bb = Bmat + (long long)b * bS;

  const int srow = tt >> 2;
  const int sgr  = (tt & 3) ^ ((tt >> 3) & 3);

  f32x4 acc[FPR][4];
  #pragma unroll
  for (int f = 0; f < FPR; ++f)
    #pragma unroll
    for (int c = 0; c < 4; ++c)
      acc[f][c] = (f32x4){0.f, 0.f, 0.f, 0.f};

  auto stage = [&](int t, int c) {
    const int k0 = t << 5;
    char* dst = lds + (t % 3) * TILE_B + c * 8192 + w * 1024;
    const __bf16* src;
    if (c < CA) src = Ab + (long long)(m0 + c * 128 + srow) * lda + k0 + sgr * 8;
    else        src = Bb + (long long)(n0 + (c - CA) * 128 + srow) * ldb + k0 + sgr * 8;
    gload_lds16(src, dst);
  };
  auto rdA = [&](const char* base, int f) -> bf16x8v {
    const int row = wm * (BM / 2) + f * 16 + lr;
    return *(const bf16x8v*)(base + row * 64 + ((lg ^ ((row >> 1) & 3)) << 4));
  };
  auto rdB = [&](const char* base, int c) -> bf16x8v {
    const int row = wn * 64 + c * 16 + lr;
    return *(const bf16x8v*)(base + BM * 64 + row * 64 + ((lg ^ ((row >> 1) & 3)) << 4));
  };

  const int NT = K >> 5;

  #pragma unroll
  for (int c = 0; c < CH; ++c) stage(0, c);
  #pragma unroll
  for (int c = 0; c < CH; ++c) stage(1, c);

  for (int t = 0; t < NT; ++t) {
    const char* buf = lds + (t % 3) * TILE_B;
    if (t + 1 < NT) vm_wait<CH>();
    else            vm_wait<0>();
    __builtin_amdgcn_s_barrier();
    __builtin_amdgcn_sched_barrier(0);

    bf16x8v Bf[4];
    #pragma unroll
    for (int c = 0; c < 4; ++c) Bf[c] = rdB(buf, c);
    bf16x8v Af[FPP];
    #pragma unroll
    for (int f = 0; f < FPP; ++f) Af[f] = rdA(buf, f);
    if (t + 2 < NT) { stage(t + 2, 0); stage(t + 2, 1); }
    LGKM0_FENCE();
    __builtin_amdgcn_s_setprio(1);
    #pragma unroll
    for (int f = 0; f < FPP; ++f)
      #pragma unroll
      for (int c = 0; c < 4; ++c)
        acc[f][c] = __builtin_amdgcn_mfma_f32_16x16x32_bf16(Af[f], Bf[c], acc[f][c], 0, 0, 0);
    __builtin_amdgcn_s_setprio(0);
    __builtin_amdgcn_s_barrier();
    __builtin_amdgcn_sched_barrier(0);

    bf16x8v Ag[FPP];
    #pragma unroll
    for (int f = 0; f < FPP; ++f) Ag[f] = rdA(buf, FPP + f);
    if (t + 2 < NT) {
      #pragma unroll
      for (int c = 2; c < CH; ++c) stage(t + 2, c);
    }
    LGKM0_FENCE();
    __builtin_amdgcn_s_setprio(1);
    #pragma unroll
    for (int f = 0; f < FPP; ++f)
      #pragma unroll
      for (int c = 0; c < 4; ++c)
        acc[FPP + f][c] = __builtin_amdgcn_mfma_f32_16x16x32_bf16(Ag[f], Bf[c], acc[FPP + f][c], 0, 0, 0);
    __builtin_amdgcn_s_setprio(0);
    __builtin_amdgcn_s_barrier();
    __builtin_amdgcn_sched_barrier(0);
  }

  #pragma unroll
  for (int f = 0; f < FPR; ++f) {
    const int rrb = m0 + wm * (BM / 2) + f * 16 + lg * 4;
    #pragma unroll
    for (int c = 0; c < 4; ++c) {
      const int cc = n0 + wn * 64 + c * 16 + lr;
      const float cbias = (BIASM == 1) ? bias[cc] : 0.f;
      #pragma unroll
      for (int r = 0; r < 4; ++r) {
        const int rr = rrb + r;
        float v = acc[f][c][r];
        if (BIASM == 1) v += cbias;
        if (BIASM == 2) v += bias[rr];
        const long long idx = (long long)rr * ldc + cc;
        if (OUTM == 0) {
          ((__bf16*)Cmat + (long long)b * cS)[idx] = (__bf16)v;
        } else if (OUTM == 2) {
          ((float*)Cmat + (long long)b * cS)[idx] = v;
        } else {
          float* Cf = (float*)Cmat + (long long)b * cS;
          const float* Rf = resid + (long long)b * cS;
          Cf[idx] = v + Rf[idx];
        }
      }
    }
  }
}

// ---------------------------------------------------------------------------
extern "C" void kernel_launch(void* const* d_in, const int* in_sizes, int n_in,
                              void* d_out, int out_size, void* d_ws, size_t ws_size,
                              hipStream_t stream)
{
  const float* x   = (const float*)d_in[0];
  const float* gnw = (const float*)d_in[1];
  const float* gnb = (const float*)d_in[2];
  const float* wq  = (const float*)d_in[3];
  const float* bq  = (const float*)d_in[4];
  const float* wk  = (const float*)d_in[5];
  const float* bk  = (const float*)d_in[6];
  const float* wv  = (const float*)d_in[7];
  const float* bv  = (const float*)d_in[8];
  const float* wo  = (const float*)d_in[9];
  const float* bo  = (const float*)d_in[10];
  (void)in_sizes; (void)n_in; (void)out_size; (void)ws_size;

  size_t used = 0;
  char* base = (char*)d_ws;
  auto carve = [&](size_t bytes) -> void* {
    used = (used + 255) & ~(size_t)255;
    void* p = base + used;
    used += bytes;
    return p;
  };

  __bf16* wqkb = (__bf16*)carve((size_t)2 * C_DIM * C_DIM * 2);
  __bf16* wvb  = (__bf16*)carve((size_t)C_DIM * C_DIM * 2);
  __bf16* wob  = (__bf16*)carve((size_t)C_DIM * C_DIM * 2);
  float*  bqk  = (float*) carve((size_t)1024 * 4);
  float2* part = (float2*)carve((size_t)256 * 8);

  __bf16* hn   = (__bf16*)carve((size_t)16 * HW_N * C_DIM * 2);   // 16MB
  __bf16* qkb  = (__bf16*)carve((size_t)16 * HW_N * 1024 * 2);    // 32MB
  __bf16* vtb  = (__bf16*)carve((size_t)16 * C_DIM * HW_N * 2);   // 16MB
  __bf16* o1b  = (__bf16*)carve((size_t)16 * HW_N * C_DIM * 2);   // 16MB
  __bf16* Sb   = (__bf16*)carve((size_t)16 * HW_N * HW_N * 2);    // 32MB

  const long long sNC = (long long)HW_N * C_DIM;   // 524288
  const long long sNN = (long long)HW_N * 1024;    // 1048576

  prep_kernel<<<dim3(1025), 256, 0, stream>>>(wq, wk, wv, wo, bq, bk,
                                              wqkb, wvb, wob, bqk);
  gn_stats<<<dim3(256), 256, 0, stream>>>(x, part);
  gn_norm<<<dim3(256), 512, 0, stream>>>(x, part, gnw, gnb, hn);

  // qk = hn x Wqk^T + bqk -> bf16 [B][1024][1024]  (512 blocks, 2/CU)
  gemm8<128, 0, 1><<<dim3(512), 512, 0, stream>>>(hn, wqkb, qkb, bqk, nullptr,
      C_DIM, C_DIM, 1024, sNC, 0, sNN, C_DIM, 4, 8);

  // v^T = Wv x hn + bv(row) -> bf16 [B][512][1024]  (256 blocks)
  gemm8<128, 0, 2><<<dim3(256), 512, 0, stream>>>(wvb, hn, vtb, bv, nullptr,
      C_DIM, C_DIM, HW_N, 0, sNC, sNC, C_DIM, 4, 4);

  // S = q x k^T -> bf16 [B][1024][1024]  (512 blocks, 2/CU)
  gemm8<128, 0, 0><<<dim3(512), 512, 0, stream>>>(qkb, qkb + 512, Sb, nullptr, nullptr,
      1024, 1024, 1024, sNN, sNN, sNN, C_DIM, 4, 8);

  // softmax rows, P bf16 in-place
  softmax_kernel<<<dim3(16 * 1024), 256, 0, stream>>>(Sb);

  // O1 = P x V -> bf16 [B][1024][512]  (256 blocks)
  gemm8<128, 0, 0><<<dim3(256), 512, 0, stream>>>(Sb, vtb, o1b, nullptr, nullptr,
      1024, 1024, C_DIM, sNN, sNC, sNC, HW_N, 2, 8);

  // out = Wo x O1^T + bo + x  (fp32 [B][512][1024], residual fused)
  gemm8<128, 1, 2><<<dim3(256), 512, 0, stream>>>(wob, o1b, (float*)d_out, bo, x,
      C_DIM, C_DIM, HW_N, 0, sNC, sNC, C_DIM, 4, 4);
}

// Round 8
// 138.422 us; speedup vs baseline: 1.2190x; 1.0807x over previous
//
#include <hip/hip_runtime.h>
#include <stdint.h>

#define C_DIM 512
#define HW_N  1024
#define CPG   64
#define EPS_GN 1e-5f
#define SCALE_QK 0.044194173824159216f   // 512^-0.5

typedef __attribute__((ext_vector_type(8))) __bf16 bf16x8v;
typedef __attribute__((ext_vector_type(4))) float  f32x4;

typedef __attribute__((address_space(1))) void gvoid_t;
typedef __attribute__((address_space(3))) void lvoid_t;

constexpr long long SNC = (long long)HW_N * C_DIM;   // 524288
constexpr long long SNN = (long long)HW_N * 1024;    // 1048576

__device__ __forceinline__ void gload_lds16(const void* g, void* l) {
  __builtin_amdgcn_global_load_lds((gvoid_t*)g, (lvoid_t*)l, 16, 0, 0);
}

__device__ __forceinline__ uint16_t f2bfbits(float f) {
  __bf16 h = (__bf16)f;
  return __builtin_bit_cast(uint16_t, h);
}

__device__ __forceinline__ float bf2f(uint16_t u) {
  return __builtin_bit_cast(float, (uint32_t)u << 16);
}

template<int N>
__device__ __forceinline__ void vm_wait() {
  if constexpr (N == 0)      asm volatile("s_waitcnt vmcnt(0)" ::: "memory");
  else if constexpr (N == 2) asm volatile("s_waitcnt vmcnt(2)" ::: "memory");
  else if constexpr (N == 3) asm volatile("s_waitcnt vmcnt(3)" ::: "memory");
  else                       asm volatile("s_waitcnt vmcnt(6)" ::: "memory");
}

#define LGKM0_FENCE()                                                          \
  asm volatile("s_waitcnt lgkmcnt(0)" ::: "memory");                           \
  __builtin_amdgcn_sched_barrier(0)

// XCD-bijective block swizzle (nwg divisible by 8).
struct BlkId { int bx, by, bz; };
__device__ __forceinline__ BlkId xcd_decode(int gx, int gy) {
  const int nwg = gridDim.x;
  const int bid = blockIdx.x;
  const int wg  = (bid & 7) * (nwg >> 3) + (bid >> 3);
  const int pb  = gx * gy;
  const int bz  = wg / pb;
  const int rem = wg - bz * pb;
  const int by  = rem / gx;
  const int bx  = rem - by * gx;
  return {bx, by, bz};
}

// ---------------------------------------------------------------------------
// Merged prep (weights->bf16, scale fold, bias concat) + GN stats.
// Blocks 0..1024: prep. Blocks 1025..1280: gn_stats.
// ---------------------------------------------------------------------------
__global__ __launch_bounds__(256)
void prep_stats_kernel(const float* __restrict__ wq, const float* __restrict__ wk,
                       const float* __restrict__ wv, const float* __restrict__ wo,
                       const float* __restrict__ bq, const float* __restrict__ bk,
                       const float* __restrict__ x,
                       __bf16* __restrict__ wqkb, __bf16* __restrict__ wvb,
                       __bf16* __restrict__ wob, float* __restrict__ bqk,
                       float2* __restrict__ part)
{
  const int blk = blockIdx.x;
  const int t = threadIdx.x;
  if (blk < 1024) {
    const int which = blk >> 8;
    const int i = (blk & 255) * 256 + t;
    const float* src = (which == 0) ? wq : (which == 1) ? wk : (which == 2) ? wv : wo;
    __bf16* dst = (which == 0) ? wqkb
               : (which == 1) ? (wqkb + (size_t)C_DIM * C_DIM)
               : (which == 2) ? wvb : wob;
    const float scale = (which == 0) ? SCALE_QK : 1.f;
    float4 v = ((const float4*)src)[i];
    uint32_t lo = (uint32_t)f2bfbits(v.x * scale) | ((uint32_t)f2bfbits(v.y * scale) << 16);
    uint32_t hi = (uint32_t)f2bfbits(v.z * scale) | ((uint32_t)f2bfbits(v.w * scale) << 16);
    ((uint2*)dst)[i] = make_uint2(lo, hi);
  } else if (blk == 1024) {
    for (int j = t; j < 1024; j += 256)
      bqk[j] = (j < 512) ? bq[j] * SCALE_QK : bk[j - 512];
  } else {
    const int lin  = blk - 1025;            // 0..255
    const int b    = lin >> 4;
    const int g    = (lin >> 1) & 7;
    const int half = lin & 1;
    const float4* xv = (const float4*)(x + ((long long)(b * C_DIM + g * CPG)) * HW_N
                                         + half * 512);
    float s1 = 0.f, s2 = 0.f;
    for (int i = t; i < 64 * 128; i += 256) {
      const int c  = i >> 7;
      const int nf = i & 127;
      float4 v = xv[c * 256 + nf];
      s1 += v.x + v.y + v.z + v.w;
      s2 += v.x * v.x + v.y * v.y + v.z * v.z + v.w * v.w;
    }
    #pragma unroll
    for (int off = 32; off; off >>= 1) {
      s1 += __shfl_xor(s1, off);
      s2 += __shfl_xor(s2, off);
    }
    __shared__ float red[2][4];
    const int w = t >> 6, l = t & 63;
    if (l == 0) { red[0][w] = s1; red[1][w] = s2; }
    __syncthreads();
    if (t == 0) {
      s1 = red[0][0] + red[0][1] + red[0][2] + red[0][3];
      s2 = red[1][0] + red[1][1] + red[1][2] + red[1][3];
      part[lin] = make_float2(s1, s2);
    }
  }
}

// ---------------------------------------------------------------------------
// GN normalize + transpose -> hn^T bf16 [N][C], bf16x8 stores.
// ---------------------------------------------------------------------------
__global__ __launch_bounds__(512)
void gn_norm(const float* __restrict__ x, const float2* __restrict__ part,
             const float* __restrict__ gnw, const float* __restrict__ gnb,
             __bf16* __restrict__ hn)
{
  const int b  = blockIdx.x >> 4;
  const int nc = blockIdx.x & 15;
  const int t  = threadIdx.x;

  __shared__ float asc[512], bsc[512];
  __shared__ float tile[64][65];

  {
    const int c = t;
    const int g = c >> 6;
    float2 p0 = part[(b * 8 + g) * 2 + 0];
    float2 p1 = part[(b * 8 + g) * 2 + 1];
    const float mean = (p0.x + p1.x) * (1.f / 65536.f);
    const float var  = (p0.y + p1.y) * (1.f / 65536.f) - mean * mean;
    const float rstd = rsqrtf(var + EPS_GN);
    const float a = rstd * gnw[c];
    asc[c] = a;
    bsc[c] = gnb[c] - mean * a;
  }
  __syncthreads();

  const long long xb = (long long)b * C_DIM * HW_N + nc * 64;
  __bf16* ob = hn + ((long long)b * HW_N + nc * 64) * C_DIM;

  for (int cg = 0; cg < 8; ++cg) {
    #pragma unroll
    for (int pass = 0; pass < 2; ++pass) {
      const int task = pass * 512 + t;
      const int c  = task >> 4;
      const int f4 = task & 15;
      float4 v = *(const float4*)(x + xb + (long long)(cg * 64 + c) * HW_N + f4 * 4);
      const float a  = asc[cg * 64 + c];
      const float bb = bsc[cg * 64 + c];
      tile[c][f4 * 4 + 0] = v.x * a + bb;
      tile[c][f4 * 4 + 1] = v.y * a + bb;
      tile[c][f4 * 4 + 2] = v.z * a + bb;
      tile[c][f4 * 4 + 3] = v.w * a + bb;
    }
    __syncthreads();
    {
      const int n  = t >> 3;
      const int gc = t & 7;
      uint32_t p[4];
      #pragma unroll
      for (int j = 0; j < 4; ++j) {
        const float f0 = tile[gc * 8 + 2 * j + 0][n];
        const float f1 = tile[gc * 8 + 2 * j + 1][n];
        p[j] = (uint32_t)f2bfbits(f0) | ((uint32_t)f2bfbits(f1) << 16);
      }
      *(uint4*)(ob + (long long)n * C_DIM + cg * 64 + gc * 8) =
          make_uint4(p[0], p[1], p[2], p[3]);
    }
    __syncthreads();
  }
}

// ---------------------------------------------------------------------------
// Row softmax over bf16 S [rows][1024], in-place -> bf16 P.
// ---------------------------------------------------------------------------
__global__ __launch_bounds__(256)
void softmax_kernel(__bf16* __restrict__ S)
{
  const long long row = blockIdx.x;
  uint2* sp = (uint2*)(S + row * HW_N);
  const int t = threadIdx.x;
  uint2 raw = sp[t];
  float v0 = bf2f((uint16_t)(raw.x & 0xffff));
  float v1 = bf2f((uint16_t)(raw.x >> 16));
  float v2 = bf2f((uint16_t)(raw.y & 0xffff));
  float v3 = bf2f((uint16_t)(raw.y >> 16));
  float m = fmaxf(fmaxf(v0, v1), fmaxf(v2, v3));
  #pragma unroll
  for (int off = 32; off; off >>= 1) m = fmaxf(m, __shfl_xor(m, off));
  __shared__ float redm[4];
  __shared__ float reds[4];
  const int w = t >> 6, l = t & 63;
  if (l == 0) redm[w] = m;
  __syncthreads();
  m = fmaxf(fmaxf(redm[0], redm[1]), fmaxf(redm[2], redm[3]));
  float e0 = __expf(v0 - m), e1 = __expf(v1 - m);
  float e2 = __expf(v2 - m), e3 = __expf(v3 - m);
  float sum = e0 + e1 + e2 + e3;
  #pragma unroll
  for (int off = 32; off; off >>= 1) sum += __shfl_xor(sum, off);
  if (l == 0) reds[w] = sum;
  __syncthreads();
  sum = reds[0] + reds[1] + reds[2] + reds[3];
  const float inv = 1.f / sum;
  uint32_t lo = (uint32_t)f2bfbits(e0 * inv) | ((uint32_t)f2bfbits(e1 * inv) << 16);
  uint32_t hi = (uint32_t)f2bfbits(e2 * inv) | ((uint32_t)f2bfbits(e3 * inv) << 16);
  sp[t] = make_uint2(lo, hi);
}

// ---------------------------------------------------------------------------
// 1-phase pipelined GEMM body: C[M][N] = A[M][K] x B[N][K]^T, BM=128,
// BN in {128,256}, BK=32, 8 waves (2x4), ring-of-3 LDS, counted vmcnt.
// Per K-step: {vmcnt(CH); barrier; stage t+2 (issue-early); 4+NF ds_reads;
// lgkmcnt(0)+sched_barrier; MFMA cluster (setprio); barrier} = 2 barriers.
// Ring invariant: stage(t+2) -> slot (t-1)%3, whose readers finished at the
// end-of-step-(t-1) barrier. vmcnt(CH) at top of t drains tile t exactly.
// ---------------------------------------------------------------------------
template<int BN, int OUTM, int BIASM>
__device__ __forceinline__ void gemm_body(char* lds,
    const __bf16* __restrict__ Ab, const __bf16* __restrict__ Bb,
    void* __restrict__ Cb, const float* __restrict__ bias,
    const float* __restrict__ resid,
    int lda, int ldb, int ldc, int K, int m0, int n0)
{
  constexpr int CB = BN / 128;       // B chunks of 8KB
  constexpr int CH = 1 + CB;         // gloads per thread per K-step
  constexpr int NF = BN / 64;        // col frags per wave
  constexpr int TILE_B = 8192 * CH;

  const int tt = threadIdx.x;
  const int w  = tt >> 6;
  const int l  = tt & 63;
  const int lr = l & 15;
  const int lg = l >> 4;
  const int wm = w >> 2;
  const int wn = w & 3;

  const int srow = tt >> 2;                     // row within 128-row chunk
  const int sgr  = (tt & 3) ^ ((tt >> 3) & 3);  // inverse-swizzled granule

  f32x4 acc[4][NF];
  #pragma unroll
  for (int f = 0; f < 4; ++f)
    #pragma unroll
    for (int c = 0; c < NF; ++c)
      acc[f][c] = (f32x4){0.f, 0.f, 0.f, 0.f};

  auto stage = [&](int t, int c) {
    char* dst = lds + (t % 3) * TILE_B + c * 8192 + w * 1024;
    const __bf16* src = (c == 0)
      ? Ab + (long long)(m0 + srow) * lda + (t << 5) + sgr * 8
      : Bb + (long long)(n0 + (c - 1) * 128 + srow) * ldb + (t << 5) + sgr * 8;
    gload_lds16(src, dst);
  };
  auto rdA = [&](const char* base, int f) -> bf16x8v {
    const int row = wm * 64 + f * 16 + lr;
    return *(const bf16x8v*)(base + row * 64 + ((lg ^ ((row >> 1) & 3)) << 4));
  };
  auto rdB = [&](const char* base, int c) -> bf16x8v {
    const int row = wn * (BN / 4) + c * 16 + lr;
    return *(const bf16x8v*)(base + 8192 + row * 64 + ((lg ^ ((row >> 1) & 3)) << 4));
  };

  const int NT = K >> 5;

  #pragma unroll
  for (int c = 0; c < CH; ++c) stage(0, c);
  #pragma unroll
  for (int c = 0; c < CH; ++c) stage(1, c);

  for (int t = 0; t < NT; ++t) {
    const char* buf = lds + (t % 3) * TILE_B;
    if (t + 1 < NT) vm_wait<CH>();
    else            vm_wait<0>();
    __builtin_amdgcn_s_barrier();
    __builtin_amdgcn_sched_barrier(0);

    if (t + 2 < NT) {
      #pragma unroll
      for (int c = 0; c < CH; ++c) stage(t + 2, c);
    }
    bf16x8v Bf[NF], Af[4];
    #pragma unroll
    for (int c = 0; c < NF; ++c) Bf[c] = rdB(buf, c);
    #pragma unroll
    for (int f = 0; f < 4; ++f)  Af[f] = rdA(buf, f);
    LGKM0_FENCE();
    __builtin_amdgcn_s_setprio(1);
    #pragma unroll
    for (int f = 0; f < 4; ++f)
      #pragma unroll
      for (int c = 0; c < NF; ++c)
        acc[f][c] = __builtin_amdgcn_mfma_f32_16x16x32_bf16(Af[f], Bf[c], acc[f][c], 0, 0, 0);
    __builtin_amdgcn_s_setprio(0);
    __builtin_amdgcn_s_barrier();
    __builtin_amdgcn_sched_barrier(0);
  }

  // epilogue: C/D layout col=lane&15, row=(lane>>4)*4+reg
  #pragma unroll
  for (int f = 0; f < 4; ++f) {
    const int rrb = m0 + wm * 64 + f * 16 + lg * 4;
    #pragma unroll
    for (int c = 0; c < NF; ++c) {
      const int cc = n0 + wn * (BN / 4) + c * 16 + lr;
      const float cbias = (BIASM == 1) ? bias[cc] : 0.f;
      #pragma unroll
      for (int r = 0; r < 4; ++r) {
        const int rr = rrb + r;
        float v = acc[f][c][r];
        if (BIASM == 1) v += cbias;
        if (BIASM == 2) v += bias[rr];
        const long long idx = (long long)rr * ldc + cc;
        if (OUTM == 0) {
          ((__bf16*)Cb)[idx] = (__bf16)v;
        } else if (OUTM == 2) {
          ((float*)Cb)[idx] = v;
        } else {
          ((float*)Cb)[idx] = v + resid[idx];
        }
      }
    }
  }
}

// ---------------------------------------------------------------------------
// Merged qk+v dispatch: 768 blocks. wg<512 -> qk tile, else v tile.
// ---------------------------------------------------------------------------
__global__ __launch_bounds__(512, 4)
void qkv_kernel(const __bf16* __restrict__ hn, const __bf16* __restrict__ wqkb,
                const __bf16* __restrict__ wvb,
                __bf16* __restrict__ qkb, __bf16* __restrict__ vtb,
                const float* __restrict__ bqk, const float* __restrict__ bv)
{
  __shared__ alignas(16) char lds[73728];
  const int wg = (blockIdx.x & 7) * 96 + (blockIdx.x >> 3);
  if (wg < 512) {
    // qk: [B][1024][1024] = hn x Wqk^T + bqk. grid 4n x 8m x 16b.
    const int bz = wg >> 5, rem = wg & 31, by = rem >> 2, bx = rem & 3;
    gemm_body<256, 0, 1>(lds, hn + (long long)bz * SNC, wqkb,
                         (void*)(qkb + (long long)bz * SNN), bqk, nullptr,
                         C_DIM, C_DIM, 1024, C_DIM, by * 128, bx * 256);
  } else {
    // v^T: [B][512][1024] = Wv x hn + bv(row). grid 4n x 4m x 16b.
    const int wg2 = wg - 512;
    const int bz = wg2 >> 4, rem = wg2 & 15, by = rem >> 2, bx = rem & 3;
    gemm_body<256, 0, 2>(lds, wvb, hn + (long long)bz * SNC,
                         (void*)(vtb + (long long)bz * SNC), bv, nullptr,
                         C_DIM, C_DIM, HW_N, C_DIM, by * 128, bx * 256);
  }
}

// ---------------------------------------------------------------------------
template<int BN, int OUTM, int BIASM>
__global__ __launch_bounds__(512, 4)
void gemm8k(const __bf16* __restrict__ A, const __bf16* __restrict__ B,
            void* __restrict__ C, const float* __restrict__ bias,
            const float* __restrict__ resid,
            int lda, int ldb, int ldc,
            long long aS, long long bS, long long cS, int K, int gx, int gy)
{
  __shared__ alignas(16) char lds[8192 * (1 + BN / 128) * 3];
  const BlkId id = xcd_decode(gx, gy);
  const __bf16* Ab = A + (long long)id.bz * aS;
  const __bf16* Bb = B + (long long)id.bz * bS;
  void* Cb = (OUTM == 0) ? (void*)((__bf16*)C + (long long)id.bz * cS)
                         : (void*)((float*)C + (long long)id.bz * cS);
  const float* rb = (OUTM == 1) ? (resid + (long long)id.bz * cS) : nullptr;
  gemm_body<BN, OUTM, BIASM>(lds, Ab, Bb, Cb, bias, rb,
                             lda, ldb, ldc, K, id.by * 128, id.bx * BN);
}

// ---------------------------------------------------------------------------
extern "C" void kernel_launch(void* const* d_in, const int* in_sizes, int n_in,
                              void* d_out, int out_size, void* d_ws, size_t ws_size,
                              hipStream_t stream)
{
  const float* x   = (const float*)d_in[0];
  const float* gnw = (const float*)d_in[1];
  const float* gnb = (const float*)d_in[2];
  const float* wq  = (const float*)d_in[3];
  const float* bq  = (const float*)d_in[4];
  const float* wk  = (const float*)d_in[5];
  const float* bk  = (const float*)d_in[6];
  const float* wv  = (const float*)d_in[7];
  const float* bv  = (const float*)d_in[8];
  const float* wo  = (const float*)d_in[9];
  const float* bo  = (const float*)d_in[10];
  (void)in_sizes; (void)n_in; (void)out_size; (void)ws_size;

  size_t used = 0;
  char* base = (char*)d_ws;
  auto carve = [&](size_t bytes) -> void* {
    used = (used + 255) & ~(size_t)255;
    void* p = base + used;
    used += bytes;
    return p;
  };

  __bf16* wqkb = (__bf16*)carve((size_t)2 * C_DIM * C_DIM * 2);
  __bf16* wvb  = (__bf16*)carve((size_t)C_DIM * C_DIM * 2);
  __bf16* wob  = (__bf16*)carve((size_t)C_DIM * C_DIM * 2);
  float*  bqk  = (float*) carve((size_t)1024 * 4);
  float2* part = (float2*)carve((size_t)256 * 8);

  __bf16* hn   = (__bf16*)carve((size_t)16 * HW_N * C_DIM * 2);   // 16MB
  __bf16* qkb  = (__bf16*)carve((size_t)16 * HW_N * 1024 * 2);    // 32MB
  __bf16* vtb  = (__bf16*)carve((size_t)16 * C_DIM * HW_N * 2);   // 16MB
  __bf16* o1b  = (__bf16*)carve((size_t)16 * HW_N * C_DIM * 2);   // 16MB
  __bf16* Sb   = (__bf16*)carve((size_t)16 * HW_N * HW_N * 2);    // 32MB

  // prep + GN stats (merged)
  prep_stats_kernel<<<dim3(1281), 256, 0, stream>>>(wq, wk, wv, wo, bq, bk, x,
                                                    wqkb, wvb, wob, bqk, part);
  // GN normalize + transpose
  gn_norm<<<dim3(256), 512, 0, stream>>>(x, part, gnw, gnb, hn);

  // qk (512 tiles) + v (256 tiles) merged: 768 blocks
  qkv_kernel<<<dim3(768), 512, 0, stream>>>(hn, wqkb, wvb, qkb, vtb, bqk, bv);

  // S = q x k^T -> bf16 [B][1024][1024]  (512 blocks, 2/CU)
  gemm8k<256, 0, 0><<<dim3(512), 512, 0, stream>>>(qkb, qkb + 512, Sb,
      nullptr, nullptr, 1024, 1024, 1024, SNN, SNN, SNN, C_DIM, 4, 8);

  // softmax rows, P bf16 in-place
  softmax_kernel<<<dim3(16 * 1024), 256, 0, stream>>>(Sb);

  // O1 = P x V -> bf16 [B][1024][512]  (BN=128: 512 blocks, 2/CU)
  gemm8k<128, 0, 0><<<dim3(512), 512, 0, stream>>>(Sb, vtb, o1b,
      nullptr, nullptr, 1024, 1024, C_DIM, SNN, SNC, SNC, HW_N, 4, 8);

  // out = Wo x O1^T + bo + x  (fp32, residual fused; BN=128: 512 blocks)
  gemm8k<128, 1, 2><<<dim3(512), 512, 0, stream>>>(wob, o1b, (void*)d_out,
      bo, x, C_DIM, C_DIM, HW_N, 0, SNC, SNC, C_DIM, 8, 4);
}